// Round 1
// baseline (2774.156 us; speedup 1.0000x reference)
//
#include <hip/hip_runtime.h>
#include <math.h>

#define B_SZ 64
#define T_SZ 256
#define H_SZ 64
#define WS 8
#define NW 248   // total output windows = T - WS

__device__ __forceinline__ float fast_rcp(float x) { return __builtin_amdgcn_rcpf(x); }
__device__ __forceinline__ float sigm(float x)   { return fast_rcp(1.0f + __expf(-x)); }
// safe tanh: saturates to +/-1 without inf/inf NaN
__device__ __forceinline__ float tanh_f(float x) { return 2.0f * fast_rcp(1.0f + __expf(-2.0f * x)) - 1.0f; }

__global__ __launch_bounds__(256, 1)
void or_lstm_kernel(const float* __restrict__ traj,
                    const float* __restrict__ Wih0, const float* __restrict__ Whh0,
                    const float* __restrict__ bih0, const float* __restrict__ bhh0,
                    const float* __restrict__ Wih1, const float* __restrict__ Whh1,
                    const float* __restrict__ bih1, const float* __restrict__ bhh1,
                    const float* __restrict__ Wlin, const float* __restrict__ blin,
                    float* __restrict__ out)
{
    const int b   = blockIdx.x;
    const int tid = threadIdx.x;

    __shared__ __align__(16) float trajS[T_SZ * 4];   // this batch row of traj
    __shared__ float h0s[H_SZ];
    __shared__ float h1s[H_SZ];
    __shared__ float gS[256];                          // activated gates
    __shared__ float outr[8][2];                       // ring of last 8 predictions

    // ---- load per-thread weight rows into registers (one-time) ----
    float wih0[4], whh0[64], wih1[64], whh1[64];
#pragma unroll
    for (int k = 0; k < 4; ++k)  wih0[k] = Wih0[tid * 4 + k];
#pragma unroll
    for (int k = 0; k < 64; ++k) whh0[k] = Whh0[tid * 64 + k];
#pragma unroll
    for (int k = 0; k < 64; ++k) wih1[k] = Wih1[tid * 64 + k];
#pragma unroll
    for (int k = 0; k < 64; ++k) whh1[k] = Whh1[tid * 64 + k];
    const float b0 = bih0[tid] + bhh0[tid];
    const float b1 = bih1[tid] + bhh1[tid];
    float wl0 = 0.f, wl1 = 0.f;
    if (tid < 64) { wl0 = Wlin[tid]; wl1 = Wlin[64 + tid]; }
    const float bl0 = blin[0], bl1 = blin[1];

    // ---- stage this batch row's trajectory into LDS (256 threads x 16B = 4KB) ----
    {
        const float4* src = (const float4*)(traj + (size_t)b * T_SZ * 4);
        float4* dst = (float4*)trajS;
        dst[tid] = src[tid];
    }

    const int gtype = tid >> 6;   // 0=i,1=f,2=g(tanh),3=o
    float cc0 = 0.f, cc1 = 0.f;   // cell states owned by threads 0..63

    for (int w = 0; w < NW; ++w) {
        // fresh zero initial state every window (reference _lstm semantics)
        if (tid < 64) { h0s[tid] = 0.f; h1s[tid] = 0.f; }
        cc0 = 0.f; cc1 = 0.f;
        __syncthreads();

        for (int s = 0; s < 8; ++s) {
            // ---- build the 4-feature input x for this (window, step) ----
            float x0, x1, x2, x3;
            if (w == 0) {
                const int t = s;
                x0 = trajS[t*4+0]; x1 = trajS[t*4+1]; x2 = trajS[t*4+2]; x3 = trajS[t*4+3];
            } else if (w < 8) {
                if (s < 8 - w) {
                    const int t = w + s;
                    x0 = trajS[t*4+0]; x1 = trajS[t*4+1]; x2 = trajS[t*4+2]; x3 = trajS[t*4+3];
                } else {
                    const int tc = 2*w + s - 1;          // reference's fb ctrl index
                    const int j  = (w + s - 8) & 7;      // out index w+s-8
                    x0 = trajS[tc*4+0]; x1 = trajS[tc*4+1];
                    x2 = outr[j][0];    x3 = outr[j][1];
                }
            } else {
                const int tc = w + s;
                const int j  = (w + s) & 7;              // (w-8+s) mod 8
                x0 = trajS[tc*4+0]; x1 = trajS[tc*4+1];
                x2 = outr[j][0];    x3 = outr[j][1];
            }

            // ---- layer 0 gates ----
            float acc = b0 + wih0[0]*x0 + wih0[1]*x1 + wih0[2]*x2 + wih0[3]*x3;
#pragma unroll
            for (int k = 0; k < 64; ++k) acc += whh0[k] * h0s[k];
            gS[tid] = (gtype == 2) ? tanh_f(acc) : sigm(acc);
            __syncthreads();
            if (tid < 64) {
                cc0 = gS[64 + tid] * cc0 + gS[tid] * gS[128 + tid];
                h0s[tid] = gS[192 + tid] * tanh_f(cc0);
            }
            __syncthreads();

            // ---- layer 1 gates ----
            acc = b1;
#pragma unroll
            for (int k = 0; k < 64; ++k) acc += wih1[k] * h0s[k];
#pragma unroll
            for (int k = 0; k < 64; ++k) acc += whh1[k] * h1s[k];
            gS[tid] = (gtype == 2) ? tanh_f(acc) : sigm(acc);
            __syncthreads();
            if (tid < 64) {
                cc1 = gS[64 + tid] * cc1 + gS[tid] * gS[128 + tid];
                h1s[tid] = gS[192 + tid] * tanh_f(cc1);
            }
            __syncthreads();
        }

        // ---- window epilogue: out[w] = prev + lin(h1_last) ----
        if (tid < 64) {
            float p0 = wl0 * h1s[tid];
            float p1 = wl1 * h1s[tid];
#pragma unroll
            for (int off = 32; off > 0; off >>= 1) {
                p0 += __shfl_down(p0, off);
                p1 += __shfl_down(p1, off);
            }
            if (tid == 0) {
                float prev0, prev1;
                if (w == 0) { prev0 = trajS[7*4+2]; prev1 = trajS[7*4+3]; }
                else        { prev0 = outr[(w-1)&7][0]; prev1 = outr[(w-1)&7][1]; }
                const float o0 = prev0 + p0 + bl0;
                const float o1 = prev1 + p1 + bl1;
                outr[w & 7][0] = o0; outr[w & 7][1] = o1;
                out[((size_t)b * NW + w) * 2 + 0] = o0;
                out[((size_t)b * NW + w) * 2 + 1] = o1;
            }
            if (w == NW - 1) {
                // final hidden/cell state of the LAST window (layer-major [2,B,H])
                float* hn = out + (size_t)B_SZ * NW * 2;
                float* cn = hn + 2 * B_SZ * H_SZ;
                hn[(0 * B_SZ + b) * H_SZ + tid] = h0s[tid];
                hn[(1 * B_SZ + b) * H_SZ + tid] = h1s[tid];
                cn[(0 * B_SZ + b) * H_SZ + tid] = cc0;
                cn[(1 * B_SZ + b) * H_SZ + tid] = cc1;
            }
        }
        __syncthreads();
    }
}

extern "C" void kernel_launch(void* const* d_in, const int* in_sizes, int n_in,
                              void* d_out, int out_size, void* d_ws, size_t ws_size,
                              hipStream_t stream) {
    const float* traj = (const float*)d_in[0];
    const float* Wih0 = (const float*)d_in[1];
    const float* Whh0 = (const float*)d_in[2];
    const float* bih0 = (const float*)d_in[3];
    const float* bhh0 = (const float*)d_in[4];
    const float* Wih1 = (const float*)d_in[5];
    const float* Whh1 = (const float*)d_in[6];
    const float* bih1 = (const float*)d_in[7];
    const float* bhh1 = (const float*)d_in[8];
    const float* Wlin = (const float*)d_in[9];
    const float* blin = (const float*)d_in[10];
    float* out = (float*)d_out;

    or_lstm_kernel<<<dim3(B_SZ), dim3(256), 0, stream>>>(
        traj, Wih0, Whh0, bih0, bhh0, Wih1, Whh1, bih1, bhh1, Wlin, blin, out);
}

// Round 3
// 2759.462 us; speedup vs baseline: 1.0053x; 1.0053x over previous
//
#include <hip/hip_runtime.h>
#include <math.h>

typedef float4 f4;
#define NW 248
#define NB 64

__device__ __forceinline__ float sigm(float x)   { return __builtin_amdgcn_rcpf(1.0f + __expf(-x)); }
__device__ __forceinline__ float tanh_f(float x) { return 2.0f * __builtin_amdgcn_rcpf(1.0f + __expf(-2.0f * x)) - 1.0f; }

// 16 NAMED float4 registers loaded from P (64 consecutive floats) — SROA-proof
#define L16(V,P) \
  f4 V##0=(P)[0],V##1=(P)[1],V##2=(P)[2],V##3=(P)[3],V##4=(P)[4],V##5=(P)[5],V##6=(P)[6],V##7=(P)[7], \
     V##8=(P)[8],V##9=(P)[9],V##10=(P)[10],V##11=(P)[11],V##12=(P)[12],V##13=(P)[13],V##14=(P)[14],V##15=(P)[15];

#define FMA1(acc,W,H) { f4 h_=(H); acc=fmaf((W).x,h_.x,acc); acc=fmaf((W).y,h_.y,acc); \
                        acc=fmaf((W).z,h_.z,acc); acc=fmaf((W).w,h_.w,acc); }

#define DOT16(q0,q1,q2,q3,V,HB) \
  FMA1(q0,V##0,(HB)[0])  FMA1(q1,V##1,(HB)[1])  FMA1(q2,V##2,(HB)[2])  FMA1(q3,V##3,(HB)[3]) \
  FMA1(q0,V##4,(HB)[4])  FMA1(q1,V##5,(HB)[5])  FMA1(q2,V##6,(HB)[6])  FMA1(q3,V##7,(HB)[7]) \
  FMA1(q0,V##8,(HB)[8])  FMA1(q1,V##9,(HB)[9])  FMA1(q2,V##10,(HB)[10]) FMA1(q3,V##11,(HB)[11]) \
  FMA1(q0,V##12,(HB)[12]) FMA1(q1,V##13,(HB)[13]) FMA1(q2,V##14,(HB)[14]) FMA1(q3,V##15,(HB)[15])

__global__ __launch_bounds__(256, 1)
void or_lstm_seq(const float* __restrict__ traj,
                 const float* __restrict__ Wih0, const float* __restrict__ Whh0,
                 const float* __restrict__ bih0, const float* __restrict__ bhh0,
                 const float* __restrict__ Wih1, const float* __restrict__ Whh1,
                 const float* __restrict__ bih1, const float* __restrict__ bhh1,
                 const float* __restrict__ Wlin, const float* __restrict__ blin,
                 float* __restrict__ out)
{
    const int row = blockIdx.x;
    const int tid = threadIdx.x;
    const int j   = tid >> 2;          // h index 0..63
    const int g   = tid & 3;           // gate 0=i,1=f,2=g(tanh),3=o
    const int r   = g * 64 + j;        // row of the 4H x K weight matrices

    __shared__ __align__(16) float trajS[256 * 4];
    __shared__ __align__(16) float X0[2][64];   // double-buffered h (layer 0)
    __shared__ __align__(16) float X1[2][64];   // double-buffered h (layer 1)
    __shared__ float outr[8][2];                // ring of last 8 predictions

    // stage trajectory row (4 KB)
    ((f4*)trajS)[tid] = ((const f4*)(traj + (size_t)row * 256 * 4))[tid];

    // weights -> named registers (~196 VGPRs)
    const f4* pA = (const f4*)(Whh0 + r * 64);
    const f4* pB = (const f4*)(Wih1 + r * 64);
    const f4* pC = (const f4*)(Whh1 + r * 64);
    L16(A, pA)
    L16(Bv, pB)
    L16(Cv, pC)
    const f4 wi0 = *(const f4*)(Wih0 + r * 4);
    const float b0 = bih0[r] + bhh0[r];
    const float b1 = bih1[r] + bhh1[r];
    float wl0 = 0.f, wl1 = 0.f;
    if (tid < 64) { wl0 = Wlin[tid]; wl1 = Wlin[64 + tid]; }
    const float bl0 = blin[0], bl1 = blin[1];

    const int lane  = tid & 63;
    const int qbase = lane & ~3;       // first lane of this 4-lane gate quad

    float cc0 = 0.f, cc1 = 0.f, h0v = 0.f, h1v = 0.f;

    for (int w = 0; w < NW; ++w) {
        if (tid < 64) { X0[0][tid] = 0.f; X1[0][tid] = 0.f; }
        cc0 = 0.f; cc1 = 0.f;
        __syncthreads();                       // B_start

        for (int s = 0; s < 8; ++s) {
            const int ps = s & 1, pn = ps ^ 1;

            // ---- input features ----
            float x0, x1, x2, x3;
            if (w == 0) {
                const int t = s;
                x0 = trajS[t*4+0]; x1 = trajS[t*4+1]; x2 = trajS[t*4+2]; x3 = trajS[t*4+3];
            } else if (w < 8) {
                if (s < 8 - w) {
                    const int t = w + s;
                    x0 = trajS[t*4+0]; x1 = trajS[t*4+1]; x2 = trajS[t*4+2]; x3 = trajS[t*4+3];
                } else {
                    const int tc = 2*w + s - 1;
                    const int jo = (w + s - 8) & 7;
                    x0 = trajS[tc*4+0]; x1 = trajS[tc*4+1];
                    x2 = outr[jo][0];   x3 = outr[jo][1];
                }
            } else {
                const int tc = w + s;
                const int jo = (w + s) & 7;
                x0 = trajS[tc*4+0]; x1 = trajS[tc*4+1];
                x2 = outr[jo][0];   x3 = outr[jo][1];
            }

            // ---- layer 0: gate, activation, in-quad shuffle, cell update ----
            float q0 = fmaf(wi0.x, x0, fmaf(wi0.y, x1, b0));
            float q1 = fmaf(wi0.z, x2, wi0.w * x3);
            float q2 = 0.f, q3 = 0.f;
            const f4* H0 = (const f4*)X0[ps];
            DOT16(q0, q1, q2, q3, A, H0)
            float acc = (q0 + q2) + (q1 + q3);
            float a = (g == 2) ? tanh_f(acc) : sigm(acc);
            float ai = __shfl(a, qbase + 0, 64);
            float af = __shfl(a, qbase + 1, 64);
            float ag = __shfl(a, qbase + 2, 64);
            float ao = __shfl(a, qbase + 3, 64);
            cc0 = af * cc0 + ai * ag;
            h0v = ao * tanh_f(cc0);
            if (g == 0) X0[pn][j] = h0v;
            __syncthreads();                   // the ONE barrier per step

            // ---- layer 1 ----
            q0 = b1; q1 = 0.f; q2 = 0.f; q3 = 0.f;
            const f4* H0n = (const f4*)X0[pn];
            const f4* H1  = (const f4*)X1[ps];
            DOT16(q0, q1, q2, q3, Bv, H0n)
            DOT16(q0, q1, q2, q3, Cv, H1)
            acc = (q0 + q2) + (q1 + q3);
            a = (g == 2) ? tanh_f(acc) : sigm(acc);
            ai = __shfl(a, qbase + 0, 64);
            af = __shfl(a, qbase + 1, 64);
            ag = __shfl(a, qbase + 2, 64);
            ao = __shfl(a, qbase + 3, 64);
            cc1 = af * cc1 + ai * ag;
            h1v = ao * tanh_f(cc1);
            if (g == 0) X1[pn][j] = h1v;
            // no barrier: next phase-1 reads X0[pn] (stable) and writes X0[ps] (unread now);
            // X1[pn] written here is first read after the NEXT step's barrier.
        }
        __syncthreads();                       // B_end: X1[0] (final h1) visible

        // ---- epilogue: out[w] = prev + Wlin·h1 + blin ----
        if (tid < 64) {
            const float hv = X1[0][tid];       // after 8 toggles state is in buffer 0
            float p0 = wl0 * hv;
            float p1 = wl1 * hv;
#pragma unroll
            for (int off = 32; off > 0; off >>= 1) {
                p0 += __shfl_down(p0, off);
                p1 += __shfl_down(p1, off);
            }
            if (tid == 0) {
                float prev0, prev1;
                if (w == 0) { prev0 = trajS[7*4+2];     prev1 = trajS[7*4+3]; }
                else        { prev0 = outr[(w-1)&7][0]; prev1 = outr[(w-1)&7][1]; }
                const float o0 = prev0 + p0 + bl0;
                const float o1 = prev1 + p1 + bl1;
                outr[w & 7][0] = o0; outr[w & 7][1] = o1;
                out[((size_t)row * NW + w) * 2 + 0] = o0;
                out[((size_t)row * NW + w) * 2 + 1] = o1;
            }
        }
        if (w == NW - 1 && g == 0) {           // final hidden/cell of last window
            float* hn = out + (size_t)NB * NW * 2;
            float* cn = hn + 2 * NB * 64;
            hn[(0 * NB + row) * 64 + j] = h0v;
            hn[(1 * NB + row) * 64 + j] = h1v;
            cn[(0 * NB + row) * 64 + j] = cc0;
            cn[(1 * NB + row) * 64 + j] = cc1;
        }
        // next window's B_start orders outr/X resets vs phase-1 readers
    }
}

extern "C" void kernel_launch(void* const* d_in, const int* in_sizes, int n_in,
                              void* d_out, int out_size, void* d_ws, size_t ws_size,
                              hipStream_t stream) {
    const float* traj = (const float*)d_in[0];
    const float* Wih0 = (const float*)d_in[1];
    const float* Whh0 = (const float*)d_in[2];
    const float* bih0 = (const float*)d_in[3];
    const float* bhh0 = (const float*)d_in[4];
    const float* Wih1 = (const float*)d_in[5];
    const float* Whh1 = (const float*)d_in[6];
    const float* bih1 = (const float*)d_in[7];
    const float* bhh1 = (const float*)d_in[8];
    const float* Wlin = (const float*)d_in[9];
    const float* blin = (const float*)d_in[10];
    float* out = (float*)d_out;

    or_lstm_seq<<<dim3(NB), dim3(256), 0, stream>>>(
        traj, Wih0, Whh0, bih0, bhh0, Wih1, Whh1, bih1, bhh1, Wlin, blin, out);
}

// Round 4
// 2009.150 us; speedup vs baseline: 1.3808x; 1.3734x over previous
//
#include <hip/hip_runtime.h>
#include <math.h>

typedef float4 f4;
#define NW 248
#define NB 64

__device__ __forceinline__ float sigm(float x)   { return __builtin_amdgcn_rcpf(1.0f + __expf(-x)); }
__device__ __forceinline__ float tanh_f(float x) { return 2.0f * __builtin_amdgcn_rcpf(1.0f + __expf(-2.0f * x)) - 1.0f; }

// 8 NAMED float4 registers loaded from P
#define L8(V,P) \
  f4 V##0=(P)[0],V##1=(P)[1],V##2=(P)[2],V##3=(P)[3],V##4=(P)[4],V##5=(P)[5],V##6=(P)[6],V##7=(P)[7];

#define FMA1(acc,W,H) { f4 h_=(H); acc=fmaf((W).x,h_.x,acc); acc=fmaf((W).y,h_.y,acc); \
                        acc=fmaf((W).z,h_.z,acc); acc=fmaf((W).w,h_.w,acc); }

// 32-FMA dot over 8 named float4 weights vs LDS float4* HB, 4 rotating accumulators
#define DOT8(q0,q1,q2,q3,V,HB) \
  FMA1(q0,V##0,(HB)[0]) FMA1(q1,V##1,(HB)[1]) FMA1(q2,V##2,(HB)[2]) FMA1(q3,V##3,(HB)[3]) \
  FMA1(q0,V##4,(HB)[4]) FMA1(q1,V##5,(HB)[5]) FMA1(q2,V##6,(HB)[6]) FMA1(q3,V##7,(HB)[7])

__global__ __launch_bounds__(512) __attribute__((amdgpu_waves_per_eu(2)))
void or_lstm_ks(const float* __restrict__ traj,
                const float* __restrict__ Wih0, const float* __restrict__ Whh0,
                const float* __restrict__ bih0, const float* __restrict__ bhh0,
                const float* __restrict__ Wih1, const float* __restrict__ Whh1,
                const float* __restrict__ bih1, const float* __restrict__ bhh1,
                const float* __restrict__ Wlin, const float* __restrict__ blin,
                float* __restrict__ out)
{
    const int row  = blockIdx.x;
    const int tid  = threadIdx.x;       // = ((j*4)+g)*2 + half
    const int half = tid & 1;           // K-half 0..1
    const int rr   = tid >> 1;          // 0..255
    const int j    = rr >> 2;           // h index 0..63
    const int g    = rr & 3;            // gate 0=i,1=f,2=g(tanh),3=o
    const int r    = g * 64 + j;        // weight-matrix row
    const int ko   = half * 32;         // K offset

    __shared__ __align__(16) float trajS[256 * 4];
    __shared__ __align__(16) float X0[2][64];   // double-buffered h, layer 0
    __shared__ __align__(16) float X1[2][64];   // double-buffered h, layer 1
    __shared__ float outr[8][2];                // ring of last 8 predictions

    if (tid < 256)
        ((f4*)trajS)[tid] = ((const f4*)(traj + (size_t)row * 256 * 4))[tid];

    // ---- per-thread half-rows of weights -> named registers (~98 floats) ----
    const f4* pA = (const f4*)(Whh0 + r * 64 + ko);
    const f4* pB = (const f4*)(Wih1 + r * 64 + ko);
    const f4* pC = (const f4*)(Whh1 + r * 64 + ko);
    L8(A, pA)
    L8(Bv, pB)
    L8(Cv, pC)
    const float wiA = Wih0[r * 4 + 2 * half];
    const float wiB = Wih0[r * 4 + 2 * half + 1];
    const float bb0 = half ? 0.f : (bih0[r] + bhh0[r]);
    const float bb1 = half ? 0.f : (bih1[r] + bhh1[r]);
    float wl0 = 0.f, wl1 = 0.f;
    if (tid < 64) { wl0 = Wlin[tid]; wl1 = Wlin[64 + tid]; }
    const float bl0 = blin[0], bl1 = blin[1];

    const int lane  = tid & 63;
    const int qbase = lane & ~7;        // first lane of this j's 8-lane group
    const int gsel  = qbase + half;     // gate G of own half at lane gsel + 2G

    float cc0 = 0.f, cc1 = 0.f, h0v = 0.f, h1v = 0.f;

    for (int w = 0; w < NW; ++w) {
        if (tid < 64) { X0[0][tid] = 0.f; X1[0][tid] = 0.f; }
        cc0 = 0.f; cc1 = 0.f;
        __syncthreads();                           // B_start

#pragma unroll
        for (int s = 0; s < 8; ++s) {
            const int ps = s & 1, pn = ps ^ 1;

            // ---- input features ----
            float x0, x1, x2, x3;
            if (w == 0) {
                const int t = s;
                x0 = trajS[t*4+0]; x1 = trajS[t*4+1]; x2 = trajS[t*4+2]; x3 = trajS[t*4+3];
            } else if (w < 8) {
                if (s < 8 - w) {
                    const int t = w + s;
                    x0 = trajS[t*4+0]; x1 = trajS[t*4+1]; x2 = trajS[t*4+2]; x3 = trajS[t*4+3];
                } else {
                    const int tc = 2*w + s - 1;
                    const int jo = (w + s - 8) & 7;
                    x0 = trajS[tc*4+0]; x1 = trajS[tc*4+1];
                    x2 = outr[jo][0];   x3 = outr[jo][1];
                }
            } else {
                const int tc = w + s;
                const int jo = (w + s) & 7;
                x0 = trajS[tc*4+0]; x1 = trajS[tc*4+1];
                x2 = outr[jo][0];   x3 = outr[jo][1];
            }
            const float xa = half ? x2 : x0;
            const float xb = half ? x3 : x1;

            // ---- layer 0: half-dot, combine, act, gather, cell ----
            float q0 = fmaf(wiA, xa, fmaf(wiB, xb, bb0));
            float q1 = 0.f, q2 = 0.f, q3 = 0.f;
            const f4* H0 = (const f4*)(&X0[ps][ko]);
            DOT8(q0, q1, q2, q3, A, H0)
            float acc = (q0 + q2) + (q1 + q3);
            acc += __shfl_xor(acc, 1, 64);         // combine K-halves
            float a = (g == 2) ? tanh_f(acc) : sigm(acc);
            float ai = __shfl(a, gsel + 0, 64);
            float af = __shfl(a, gsel + 2, 64);
            float ag = __shfl(a, gsel + 4, 64);
            float ao = __shfl(a, gsel + 6, 64);
            cc0 = af * cc0 + ai * ag;
            h0v = ao * tanh_f(cc0);
            if (g == 0 && half == 0) X0[pn][j] = h0v;
            __syncthreads();                       // the ONE barrier per step

            // ---- layer 1 ----
            q0 = bb1; q1 = 0.f; q2 = 0.f; q3 = 0.f;
            const f4* H0n = (const f4*)(&X0[pn][ko]);
            const f4* H1  = (const f4*)(&X1[ps][ko]);
            DOT8(q0, q1, q2, q3, Bv, H0n)
            DOT8(q0, q1, q2, q3, Cv, H1)
            acc = (q0 + q2) + (q1 + q3);
            acc += __shfl_xor(acc, 1, 64);
            a = (g == 2) ? tanh_f(acc) : sigm(acc);
            ai = __shfl(a, gsel + 0, 64);
            af = __shfl(a, gsel + 2, 64);
            ag = __shfl(a, gsel + 4, 64);
            ao = __shfl(a, gsel + 6, 64);
            cc1 = af * cc1 + ai * ag;
            h1v = ao * tanh_f(cc1);
            if (g == 0 && half == 0) X1[pn][j] = h1v;
            // no barrier: next step's layer0 reads X0[pn] (stable), writes X0[ps]
            // (no longer read); X1[pn] first read after next step's barrier.
        }
        __syncthreads();                           // B_end: X1[0] visible

        // ---- epilogue: out[w] = prev + Wlin.h1 + blin (wave 0 only) ----
        if (tid < 64) {
            const float hv = X1[0][tid];           // final h1 lands in buffer 0
            float p0 = wl0 * hv;
            float p1 = wl1 * hv;
#pragma unroll
            for (int off = 32; off > 0; off >>= 1) {
                p0 += __shfl_down(p0, off);
                p1 += __shfl_down(p1, off);
            }
            if (tid == 0) {
                float prev0, prev1;
                if (w == 0) { prev0 = trajS[7*4+2];     prev1 = trajS[7*4+3]; }
                else        { prev0 = outr[(w-1)&7][0]; prev1 = outr[(w-1)&7][1]; }
                const float o0 = prev0 + p0 + bl0;
                const float o1 = prev1 + p1 + bl1;
                outr[w & 7][0] = o0; outr[w & 7][1] = o1;
                out[((size_t)row * NW + w) * 2 + 0] = o0;
                out[((size_t)row * NW + w) * 2 + 1] = o1;
            }
        }
        if (w == NW - 1 && g == 0 && half == 0) {  // final hidden/cell state
            float* hn = out + (size_t)NB * NW * 2;
            float* cn = hn + 2 * NB * 64;
            hn[(0 * NB + row) * 64 + j] = h0v;
            hn[(1 * NB + row) * 64 + j] = h1v;
            cn[(0 * NB + row) * 64 + j] = cc0;
            cn[(1 * NB + row) * 64 + j] = cc1;
        }
        // next window's B_start orders outr/X resets vs readers
    }
}

extern "C" void kernel_launch(void* const* d_in, const int* in_sizes, int n_in,
                              void* d_out, int out_size, void* d_ws, size_t ws_size,
                              hipStream_t stream) {
    const float* traj = (const float*)d_in[0];
    const float* Wih0 = (const float*)d_in[1];
    const float* Whh0 = (const float*)d_in[2];
    const float* bih0 = (const float*)d_in[3];
    const float* bhh0 = (const float*)d_in[4];
    const float* Wih1 = (const float*)d_in[5];
    const float* Whh1 = (const float*)d_in[6];
    const float* bih1 = (const float*)d_in[7];
    const float* bhh1 = (const float*)d_in[8];
    const float* Wlin = (const float*)d_in[9];
    const float* blin = (const float*)d_in[10];
    float* out = (float*)d_out;

    or_lstm_ks<<<dim3(NB), dim3(512), 0, stream>>>(
        traj, Wih0, Whh0, bih0, bhh0, Wih1, Whh1, bih1, bhh1, Wlin, blin, out);
}

// Round 5
// 1980.507 us; speedup vs baseline: 1.4007x; 1.0145x over previous
//
#include <hip/hip_runtime.h>
#include <math.h>

typedef float4 f4;
#define NW 248
#define NB 64

__device__ __forceinline__ float sigm(float x)   { return __builtin_amdgcn_rcpf(1.0f + __expf(-x)); }
__device__ __forceinline__ float tanh_f(float x) { return 2.0f * __builtin_amdgcn_rcpf(1.0f + __expf(-2.0f * x)) - 1.0f; }

// 8 NAMED float4 registers loaded from P
#define L8(V,P) \
  f4 V##0=(P)[0],V##1=(P)[1],V##2=(P)[2],V##3=(P)[3],V##4=(P)[4],V##5=(P)[5],V##6=(P)[6],V##7=(P)[7];

// Opacity launder: asm outputs are NOT rematerializable -> RA must keep in VGPRs.
#define OPQ1(X) asm volatile("" : "+v"(X));
#define OPQ4(V) OPQ1(V.x) OPQ1(V.y) OPQ1(V.z) OPQ1(V.w)
#define OPQ8(V) OPQ4(V##0) OPQ4(V##1) OPQ4(V##2) OPQ4(V##3) OPQ4(V##4) OPQ4(V##5) OPQ4(V##6) OPQ4(V##7)

#define FMA1(acc,W,H) { f4 h_=(H); acc=fmaf((W).x,h_.x,acc); acc=fmaf((W).y,h_.y,acc); \
                        acc=fmaf((W).z,h_.z,acc); acc=fmaf((W).w,h_.w,acc); }

// 32-FMA dot over 8 named float4 weights vs LDS float4* HB, 4 rotating accumulators
#define DOT8(q0,q1,q2,q3,V,HB) \
  FMA1(q0,V##0,(HB)[0]) FMA1(q1,V##1,(HB)[1]) FMA1(q2,V##2,(HB)[2]) FMA1(q3,V##3,(HB)[3]) \
  FMA1(q0,V##4,(HB)[4]) FMA1(q1,V##5,(HB)[5]) FMA1(q2,V##6,(HB)[6]) FMA1(q3,V##7,(HB)[7])

__global__ __launch_bounds__(512) __attribute__((amdgpu_waves_per_eu(2)))
void or_lstm_ks(const float* __restrict__ traj,
                const float* __restrict__ Wih0, const float* __restrict__ Whh0,
                const float* __restrict__ bih0, const float* __restrict__ bhh0,
                const float* __restrict__ Wih1, const float* __restrict__ Whh1,
                const float* __restrict__ bih1, const float* __restrict__ bhh1,
                const float* __restrict__ Wlin, const float* __restrict__ blin,
                float* __restrict__ out)
{
    const int row  = blockIdx.x;
    const int tid  = threadIdx.x;       // = ((j*4)+g)*2 + half
    const int half = tid & 1;           // K-half 0..1
    const int rr   = tid >> 1;          // 0..255
    const int j    = rr >> 2;           // h index 0..63
    const int g    = rr & 3;            // gate 0=i,1=f,2=g(tanh),3=o
    const int r    = g * 64 + j;        // weight-matrix row
    const int ko   = half * 32;         // K offset

    __shared__ __align__(16) float trajS[256 * 4];
    __shared__ __align__(16) float X0[2][64];   // double-buffered h, layer 0
    __shared__ __align__(16) float X1[2][64];   // double-buffered h, layer 1
    __shared__ float outr[8][2];                // ring of last 8 predictions

    if (tid < 256)
        ((f4*)trajS)[tid] = ((const f4*)(traj + (size_t)row * 256 * 4))[tid];

    // ---- per-thread half-rows of weights -> registers, laundered opaque ----
    const f4* pA = (const f4*)(Whh0 + r * 64 + ko);
    const f4* pB = (const f4*)(Wih1 + r * 64 + ko);
    const f4* pC = (const f4*)(Whh1 + r * 64 + ko);
    L8(A, pA)
    L8(Bv, pB)
    L8(Cv, pC)
    OPQ8(A)
    OPQ8(Bv)
    OPQ8(Cv)
    float wiA = Wih0[r * 4 + 2 * half];
    float wiB = Wih0[r * 4 + 2 * half + 1];
    float bb0 = half ? 0.f : (bih0[r] + bhh0[r]);
    float bb1 = half ? 0.f : (bih1[r] + bhh1[r]);
    OPQ1(wiA) OPQ1(wiB) OPQ1(bb0) OPQ1(bb1)
    float wl0 = 0.f, wl1 = 0.f;
    if (tid < 64) { wl0 = Wlin[tid]; wl1 = Wlin[64 + tid]; }
    const float bl0 = blin[0], bl1 = blin[1];

    const int lane  = tid & 63;
    const int qbase = lane & ~7;        // first lane of this j's 8-lane group
    const int gsel  = qbase + half;     // gate G of own half at lane gsel + 2G

    float cc0 = 0.f, cc1 = 0.f, h0v = 0.f, h1v = 0.f;

    for (int w = 0; w < NW; ++w) {
        if (tid < 64) { X0[0][tid] = 0.f; X1[0][tid] = 0.f; }
        cc0 = 0.f; cc1 = 0.f;
        __syncthreads();                           // B_start

#pragma unroll
        for (int s = 0; s < 8; ++s) {
            const int ps = s & 1, pn = ps ^ 1;

            // ---- input features ----
            float x0, x1, x2, x3;
            if (w == 0) {
                const int t = s;
                x0 = trajS[t*4+0]; x1 = trajS[t*4+1]; x2 = trajS[t*4+2]; x3 = trajS[t*4+3];
            } else if (w < 8) {
                if (s < 8 - w) {
                    const int t = w + s;
                    x0 = trajS[t*4+0]; x1 = trajS[t*4+1]; x2 = trajS[t*4+2]; x3 = trajS[t*4+3];
                } else {
                    const int tc = 2*w + s - 1;
                    const int jo = (w + s - 8) & 7;
                    x0 = trajS[tc*4+0]; x1 = trajS[tc*4+1];
                    x2 = outr[jo][0];   x3 = outr[jo][1];
                }
            } else {
                const int tc = w + s;
                const int jo = (w + s) & 7;
                x0 = trajS[tc*4+0]; x1 = trajS[tc*4+1];
                x2 = outr[jo][0];   x3 = outr[jo][1];
            }
            const float xa = half ? x2 : x0;
            const float xb = half ? x3 : x1;

            // ---- layer 0: half-dot, combine, act, gather, cell ----
            float q0 = fmaf(wiA, xa, fmaf(wiB, xb, bb0));
            float q1 = 0.f, q2 = 0.f, q3 = 0.f;
            const f4* H0 = (const f4*)(&X0[ps][ko]);
            DOT8(q0, q1, q2, q3, A, H0)
            float acc = (q0 + q2) + (q1 + q3);
            acc += __shfl_xor(acc, 1, 64);         // combine K-halves
            float a = (g == 2) ? tanh_f(acc) : sigm(acc);
            float ai = __shfl(a, gsel + 0, 64);
            float af = __shfl(a, gsel + 2, 64);
            float ag = __shfl(a, gsel + 4, 64);
            float ao = __shfl(a, gsel + 6, 64);
            cc0 = af * cc0 + ai * ag;
            h0v = ao * tanh_f(cc0);
            if (g == 0 && half == 0) X0[pn][j] = h0v;
            __syncthreads();                       // the ONE barrier per step

            // ---- layer 1 ----
            q0 = bb1; q1 = 0.f; q2 = 0.f; q3 = 0.f;
            const f4* H0n = (const f4*)(&X0[pn][ko]);
            const f4* H1  = (const f4*)(&X1[ps][ko]);
            DOT8(q0, q1, q2, q3, Bv, H0n)
            DOT8(q0, q1, q2, q3, Cv, H1)
            acc = (q0 + q2) + (q1 + q3);
            acc += __shfl_xor(acc, 1, 64);
            a = (g == 2) ? tanh_f(acc) : sigm(acc);
            ai = __shfl(a, gsel + 0, 64);
            af = __shfl(a, gsel + 2, 64);
            ag = __shfl(a, gsel + 4, 64);
            ao = __shfl(a, gsel + 6, 64);
            cc1 = af * cc1 + ai * ag;
            h1v = ao * tanh_f(cc1);
            if (g == 0 && half == 0) X1[pn][j] = h1v;
            // no barrier: next step's layer0 reads X0[pn] (stable), writes X0[ps]
            // (no longer read); X1[pn] first read after next step's barrier.
        }
        __syncthreads();                           // B_end: X1[0] visible

        // ---- epilogue: out[w] = prev + Wlin.h1 + blin (wave 0 only) ----
        if (tid < 64) {
            const float hv = X1[0][tid];           // final h1 lands in buffer 0
            float p0 = wl0 * hv;
            float p1 = wl1 * hv;
#pragma unroll
            for (int off = 32; off > 0; off >>= 1) {
                p0 += __shfl_down(p0, off);
                p1 += __shfl_down(p1, off);
            }
            if (tid == 0) {
                float prev0, prev1;
                if (w == 0) { prev0 = trajS[7*4+2];     prev1 = trajS[7*4+3]; }
                else        { prev0 = outr[(w-1)&7][0]; prev1 = outr[(w-1)&7][1]; }
                const float o0 = prev0 + p0 + bl0;
                const float o1 = prev1 + p1 + bl1;
                outr[w & 7][0] = o0; outr[w & 7][1] = o1;
                out[((size_t)row * NW + w) * 2 + 0] = o0;
                out[((size_t)row * NW + w) * 2 + 1] = o1;
            }
        }
        if (w == NW - 1 && g == 0 && half == 0) {  // final hidden/cell state
            float* hn = out + (size_t)NB * NW * 2;
            float* cn = hn + 2 * NB * 64;
            hn[(0 * NB + row) * 64 + j] = h0v;
            hn[(1 * NB + row) * 64 + j] = h1v;
            cn[(0 * NB + row) * 64 + j] = cc0;
            cn[(1 * NB + row) * 64 + j] = cc1;
        }
        // next window's B_start orders outr/X resets vs readers
    }
}

extern "C" void kernel_launch(void* const* d_in, const int* in_sizes, int n_in,
                              void* d_out, int out_size, void* d_ws, size_t ws_size,
                              hipStream_t stream) {
    const float* traj = (const float*)d_in[0];
    const float* Wih0 = (const float*)d_in[1];
    const float* Whh0 = (const float*)d_in[2];
    const float* bih0 = (const float*)d_in[3];
    const float* bhh0 = (const float*)d_in[4];
    const float* Wih1 = (const float*)d_in[5];
    const float* Whh1 = (const float*)d_in[6];
    const float* bih1 = (const float*)d_in[7];
    const float* bhh1 = (const float*)d_in[8];
    const float* Wlin = (const float*)d_in[9];
    const float* blin = (const float*)d_in[10];
    float* out = (float*)d_out;

    or_lstm_ks<<<dim3(NB), dim3(512), 0, stream>>>(
        traj, Wih0, Whh0, bih0, bhh0, Wih1, Whh1, bih1, bhh1, Wlin, blin, out);
}